// Round 24
// baseline (211.469 us; speedup 1.0000x reference)
//
#include <hip/hip_runtime.h>
#include <hip/hip_bf16.h>
#include <hip/hip_fp8.h>

// sim[b,l,m] = sum_d relu(prev@W+b)[b,l,d] * relu(after@W+b)[b,m,d]
// bz=16, L=2048, d=768.
//
// Pipeline:
//   1. wt_kernel : Wt[n][k] = bf16(W[k][n])                    (ws, 1.2 MB)
//   2. gemm_ff   : P8 = fp8(relu(bf16(seq) @ Wt^T + bias))     (ws, 48 MB)
//   3. gemm_sim  : sim[b] = P8p[b] @ P8a[b]^T -> fp32 d_out    (MX-fp8 MFMA)
//
// ROUND 23 config (185.9us: nt C-stores won -30us) + ONE epilogue change:
// gemm_ff's P8 stores also NON-TEMPORAL. P8 is re-read by gemm_sim from HBM
// anyway (48MB > 32MB aggregate L2; sim's FETCH 54MB = full P8), so keeping
// it out of L2 is semantics-identical and preserves A-panel/Wt residency
// during ff — the same mechanism that just paid in gemm_sim.

typedef __attribute__((ext_vector_type(8)))  short bf16x8v;
typedef __attribute__((ext_vector_type(8)))  short s16x8;
typedef __attribute__((ext_vector_type(4)))  float f32x4;
typedef __attribute__((ext_vector_type(16))) float f32x16;
typedef __attribute__((ext_vector_type(4)))  float float4v;
typedef __attribute__((ext_vector_type(8)))  int   int8v;
typedef __attribute__((ext_vector_type(4)))  int   int4v;

__device__ __forceinline__ unsigned short f2bf(float f) {
  unsigned int u = __float_as_uint(f);
  u += 0x7fffu + ((u >> 16) & 1u);
  return (unsigned short)(u >> 16);
}

__device__ __forceinline__ unsigned char f2e4m3(float f) {
  __hip_fp8_e4m3 q(f);                        // OCP e4m3fn, RNE+sat
  return (unsigned char)q.__x;
}

__device__ __forceinline__ void async_copy16(void* lds, const void* g) {
  __builtin_amdgcn_global_load_lds(
      (const __attribute__((address_space(1))) void*)g,
      (__attribute__((address_space(3))) void*)lds, 16, 0, 0);
}

// proven macro set (round-5 skeleton)
#define BAR()    asm volatile("s_barrier" ::: "memory")
#define WAITV3() asm volatile("s_waitcnt vmcnt(3)" ::: "memory")
#define WAITV0() asm volatile("s_waitcnt vmcnt(0)" ::: "memory")
#define WAITL()  do { asm volatile("s_waitcnt lgkmcnt(0)" ::: "memory"); \
                      __builtin_amdgcn_sched_barrier(0); } while (0)
// pinned variants (gemm_ff)
#define FBARF()   do { __builtin_amdgcn_sched_barrier(0);                 \
                       __builtin_amdgcn_s_barrier();                      \
                       __builtin_amdgcn_sched_barrier(0); } while (0)
#define FWAITV(n) do { asm volatile("s_waitcnt vmcnt(" #n ")" ::: "memory"); \
                       __builtin_amdgcn_sched_barrier(0); } while (0)
#define FLGKM0()  do { asm volatile("s_waitcnt lgkmcnt(0)" ::: "memory");  \
                       __builtin_amdgcn_sched_barrier(0); } while (0)

// ---------------- W transpose + convert: Wt[n][k] = bf16(W[k][n]) ------------
__global__ void wt_kernel(const float* __restrict__ W, short* __restrict__ Wt) {
  int idx = blockIdx.x * 256 + threadIdx.x;   // n*768 + k
  int n = idx / 768;
  int k = idx - n * 768;
  Wt[idx] = (short)f2bf(W[k * 768 + n]);
}

// ======== gemm_ff: P8 = fp8(relu(bf16(seq) @ Wt^T + bias)) ==================
// 128x256 tile, BK=32, KT=24, 8 waves 2Mx4N (64x64/wave, 32x32x16 frags).
// A: fp32 -> regs -> cvt -> swizzled ds_write (once per element, off path).
__global__ __launch_bounds__(512, 4)
void gemm_ff(const float* __restrict__ Sprev, const float* __restrict__ Safter,
             const short* __restrict__ Wt, const float* __restrict__ bias,
             unsigned char* __restrict__ Out) {
  constexpr int BK = 32, KT = 24;             // K = 768
  __shared__ __align__(16) short lA[2][128 * BK];   // 8 KB per buf
  __shared__ __align__(16) short lB[2][256 * BK];   // 16 KB per buf

  // T1: XCD-chunked swizzle (1536 = 8 * 192, bijective); 3 N-siblings of one
  // by are consecutive -> share the 384KB A-panel in the XCD's L2.
  const int bid  = blockIdx.x;                // 0..1535
  const int virt = (bid & 7) * 192 + (bid >> 3);
  const int by   = virt / 3;                  // 0..511 (M-tile, 128 rows)
  const int bx   = virt - by * 3;             // 0..2   (N-tile, 256 cols)

  const int tid  = threadIdx.x;
  const int lane = tid & 63;
  const int w    = tid >> 6;                  // 0..7
  const int wr   = w >> 2;                    // 0..1 (M half: 64 rows)
  const int wc   = w & 3;                     // 0..3 (N quarter: 64 cols)
  const int tn   = bx * 256;

  const float* Af = (by < 256 ? Sprev : Safter) + (size_t)((by & 255) * 128) * 768;
  const int    tm = by * 128;                 // global output row base

  const int l31  = lane & 31;
  const int khi  = lane >> 5;                 // k-half selector (bytes *16)
  const int arow = wr * 64 + l31;             // A frag row base (0..127)
  const int brow = wc * 64 + l31;             // B frag row base (0..255)
  const int swA  = ((arow >> 1) & 3) << 4;    // 64B-row swizzle, +32 invariant
  const int swB  = ((brow >> 1) & 3) << 4;

  // A: 128x32 fp32 tile; thread: row=tid>>2, 8 floats at col (tid&3)*8.
#define FF_LOAD_A(k0)                                                         \
  {                                                                           \
    int _row = tid >> 2;                                                      \
    const float* _g = Af + (size_t)_row * 768 + (k0) + (tid & 3) * 8;         \
    ar[0] = *(const float4v*)_g;                                              \
    ar[1] = *(const float4v*)(_g + 4);                                        \
  }

  // cvt + swizzled ds_write_b128 (dest XOR'd; read uses same XOR)
#define FF_CVT_WRITE(buf)                                                     \
  {                                                                           \
    int _row = tid >> 2;                                                      \
    int _cb  = ((tid & 3) * 16) ^ (((_row >> 1) & 3) << 4);                   \
    s16x8 _o;                                                                 \
    _o[0] = (short)f2bf(ar[0][0]); _o[1] = (short)f2bf(ar[0][1]);             \
    _o[2] = (short)f2bf(ar[0][2]); _o[3] = (short)f2bf(ar[0][3]);             \
    _o[4] = (short)f2bf(ar[1][0]); _o[5] = (short)f2bf(ar[1][1]);             \
    _o[6] = (short)f2bf(ar[1][2]); _o[7] = (short)f2bf(ar[1][3]);             \
    *(s16x8*)((char*)lA[buf] + _row * 64 + _cb) = _o;                         \
  }

  // B: 256x32 bf16 tile = 16KB = 2 gload_lds rounds, pre-swizzled source
#define FF_STAGE_B(buf, k0)                                                   \
  {                                                                           \
    _Pragma("unroll")                                                         \
    for (int _j = 0; _j < 2; ++_j) {                                          \
      int _c   = _j * 512 + tid;                                              \
      int _row = _c >> 2;                                                     \
      int _cb  = ((_c & 3) * 16) ^ (((_row >> 1) & 3) << 4);                  \
      async_copy16((char*)lB[buf] + _j * 8192 + w * 1024,                     \
                   (const char*)(Wt + (size_t)(tn + _row) * 768 + (k0)) + _cb); \
    }                                                                         \
  }

  // per ks (K=16): 2 A-frags + 2 B-frags, each one ds_read_b128
#define FF_FRAGS(buf, ks)                                                     \
  {                                                                           \
    const char* _bA = (const char*)lA[buf];                                   \
    const char* _bB = (const char*)lB[buf];                                   \
    const int _kxA = ((ks) * 32 + khi * 16) ^ swA;                            \
    const int _kxB = ((ks) * 32 + khi * 16) ^ swB;                            \
    _Pragma("unroll")                                                         \
    for (int _mt = 0; _mt < 2; ++_mt)                                         \
      af[_mt] = *(const bf16x8v*)(_bA + (arow + _mt * 32) * 64 + _kxA);       \
    _Pragma("unroll")                                                         \
    for (int _nt = 0; _nt < 2; ++_nt)                                         \
      bg[_nt] = *(const bf16x8v*)(_bB + (brow + _nt * 32) * 64 + _kxB);       \
  }

#define FF_MFMA()                                                             \
  {                                                                           \
    __builtin_amdgcn_s_setprio(1);                                            \
    _Pragma("unroll")                                                         \
    for (int _mt = 0; _mt < 2; ++_mt)                                         \
      _Pragma("unroll")                                                       \
      for (int _nt = 0; _nt < 2; ++_nt)                                       \
        acc[_mt][_nt] = __builtin_amdgcn_mfma_f32_32x32x16_bf16(              \
            af[_mt], bg[_nt], acc[_mt][_nt], 0, 0, 0);                        \
    __builtin_amdgcn_s_setprio(0);                                            \
  }

  f32x16 acc[2][2] = {};
  float4v ar[2];
  bf16x8v af[2], bg[2];

  // prologue: A(0)->regs->lA[0]; A(1)->regs; B(0),B(1) staged.
  FF_LOAD_A(0);                               // vm: A0=2
  FWAITV(0);
  FF_CVT_WRITE(0);
  FF_LOAD_A(BK);                              // vm: A1=2
  FF_STAGE_B(0, 0);                           // vm: +B0=2
  FF_STAGE_B(1, BK);                          // vm: +B1=2  (out: 6)
  FLGKM0();                                   // own lA[0] writes done
  FWAITV(2);                                  // retires A1+B0: B0 landed
  FBARF();                                    // tile0 ready for everyone

  // invariant at loop top (kt>=1): outstanding = [A(kt+1)(2), B(kt+1)(2)];
  // kt=0: [B1(2)] with A(1) already landed (prologue FWAITV(2)).
  for (int kt = 0; kt < KT; ++kt) {
    const int cur = kt & 1, nxt = cur ^ 1;
    FF_FRAGS(cur, 0);                         // 4 ds_read
    if (kt + 1 < KT) {
      FWAITV(2);                              // A(kt+1) landed (retires oldest)
      FF_CVT_WRITE(nxt);                      // 1 ds_write -> lA[nxt]
    }
    FLGKM0();                                 // frags + write done
    FF_MFMA();                                // ks0
    if (kt + 2 < KT) FF_LOAD_A((kt + 2) * BK);  // 2 vm (ar freed by CVT)
    FF_FRAGS(cur, 1);                         // 4 ds_read
    FLGKM0();                                 // all reads of buf[cur] done
    if (kt + 1 < KT) {
      if (kt + 2 < KT) { FWAITV(2); }         // B(kt+1) landed (leaves A(kt+2))
      else             { FWAITV(0); }         // tail drain
      FBARF();                                // tile kt+1 ready; buf[cur] free
      if (kt + 2 < KT) FF_STAGE_B(cur, (kt + 2) * BK);  // 2 vm
    }
    FF_MFMA();                                // ks1
  }

  // epilogue: bias+relu -> fp8 e4m3 via NON-TEMPORAL stores (P8 comes from
  // HBM in gemm_sim anyway; keep ff's A-panels/Wt resident in L2).
#pragma unroll
  for (int mt = 0; mt < 2; ++mt) {
    int rowb = tm + wr * 64 + mt * 32 + 4 * (lane >> 5);
#pragma unroll
    for (int nt = 0; nt < 2; ++nt) {
      int col = tn + wc * 64 + nt * 32 + l31;
      float bv = bias[col];
#pragma unroll
      for (int reg = 0; reg < 16; ++reg) {
        int row = rowb + (reg & 3) + 8 * (reg >> 2);
        float v = fmaxf(acc[mt][nt][reg] + bv, 0.0f);
        __builtin_nontemporal_store(f2e4m3(v), &Out[(size_t)row * 768 + col]);
      }
    }
  }
#undef FF_LOAD_A
#undef FF_CVT_WRITE
#undef FF_STAGE_B
#undef FF_FRAGS
#undef FF_MFMA
}

// ======== gemm_sim: sim[b] = P8p[b] @ P8a[b]^T (MX-scaled fp8 MFMA) =========
// Round-23 kernel (nt C-stores), byte-identical.
__global__ __launch_bounds__(512, 4)
void gemm_sim(const unsigned char* __restrict__ A, const unsigned char* __restrict__ B,
              float* __restrict__ C) {
  constexpr int BK = 64, KT = 12, LD = 2048;  // K = 768 (BK elems = bytes)
  __shared__ __align__(16) unsigned char lA[2][256 * BK];   // 16 KB per buf
  __shared__ __align__(16) unsigned char lB[2][128 * BK];   // 8 KB per buf

  // T1: XCD-chunked swizzle (2048 = 8 * 256, bijective).
  const int bid  = blockIdx.x;                // 0..2047
  const int virt = (bid & 7) * 256 + (bid >> 3);
  const int bz   = virt >> 7;                 // 0..15 batch
  const int rem  = virt & 127;
  const int by   = rem >> 4;                  // 0..7  M-tile (256 rows)
  const int bx   = rem & 15;                  // 0..15 N-tile (128 rows)

  const int tid  = threadIdx.x;
  const int lane = tid & 63;
  const int w    = tid >> 6;                  // 0..7
  const int wr   = w >> 1;                    // 0..3  (M quarter: 64 rows)
  const int wc   = w & 1;                     // 0..1  (N half: 64 cols)
  const int tm   = by * 256;
  const int tn   = bx * 128;

  const unsigned char* Ab = A + (size_t)bz * LD * 768 + (size_t)tm * 768;
  const unsigned char* Bb = B + (size_t)bz * LD * 768 + (size_t)tn * 768;

  const int l31  = lane & 31;                 // fragment row within 32
  const int kq32 = (lane >> 5) * 32;          // byte base of lane's 32B k-slice
  const int arow = wr * 64 + l31;             // A row base (0..255)
  const int brow = wc * 64 + l31;             // B row base (0..127)
  const int swA  = ((arow >> 1) & 3) << 4;
  const int swB  = ((brow >> 1) & 3) << 4;

#define STAGE(buf, k0)                                                        \
  {                                                                           \
    _Pragma("unroll")                                                         \
    for (int _j = 0; _j < 2; ++_j) {                                          \
      int _c   = _j * 512 + tid;                                              \
      int _row = _c >> 2;                                                     \
      int _cb  = ((_c & 3) * 16) ^ (((_row >> 1) & 3) << 4);                  \
      async_copy16((char*)lA[buf] + _j * 8192 + w * 1024,                     \
                   Ab + (size_t)_row * 768 + (k0) + _cb);                     \
    }                                                                         \
    {                                                                         \
      int _row = tid >> 2;                                                    \
      int _cb  = ((tid & 3) * 16) ^ (((_row >> 1) & 3) << 4);                 \
      async_copy16((char*)lB[buf] + w * 1024,                                 \
                   Bb + (size_t)_row * 768 + (k0) + _cb);                     \
    }                                                                         \
  }

#define LOAD_FRAGS_ALL(buf)                                                   \
  {                                                                           \
    const char* _bA = (const char*)lA[buf];                                   \
    const char* _bB = (const char*)lB[buf];                                   \
    _Pragma("unroll")                                                         \
    for (int _mt = 0; _mt < 2; ++_mt) {                                       \
      const char* _r = _bA + (arow + _mt * 32) * BK;                          \
      int4v _lo = *(const int4v*)(_r + ((kq32 + 0)  ^ swA));                  \
      int4v _hi = *(const int4v*)(_r + ((kq32 + 16) ^ swA));                  \
      af[_mt][0] = _lo[0]; af[_mt][1] = _lo[1];                               \
      af[_mt][2] = _lo[2]; af[_mt][3] = _lo[3];                               \
      af[_mt][4] = _hi[0]; af[_mt][5] = _hi[1];                               \
      af[_mt][6] = _hi[2]; af[_mt][7] = _hi[3];                               \
    }                                                                         \
    _Pragma("unroll")                                                         \
    for (int _nt = 0; _nt < 2; ++_nt) {                                       \
      const char* _r = _bB + (brow + _nt * 32) * BK;                          \
      int4v _lo = *(const int4v*)(_r + ((kq32 + 0)  ^ swB));                  \
      int4v _hi = *(const int4v*)(_r + ((kq32 + 16) ^ swB));                  \
      bg[_nt][0] = _lo[0]; bg[_nt][1] = _lo[1];                               \
      bg[_nt][2] = _lo[2]; bg[_nt][3] = _lo[3];                               \
      bg[_nt][4] = _hi[0]; bg[_nt][5] = _hi[1];                               \
      bg[_nt][6] = _hi[2]; bg[_nt][7] = _hi[3];                               \
    }                                                                         \
  }

#define MFMA_ALL()                                                            \
  {                                                                           \
    __builtin_amdgcn_s_setprio(1);                                            \
    _Pragma("unroll")                                                         \
    for (int _mt = 0; _mt < 2; ++_mt)                                         \
      _Pragma("unroll")                                                       \
      for (int _nt = 0; _nt < 2; ++_nt)                                       \
        acc[_mt][_nt] = __builtin_amdgcn_mfma_scale_f32_32x32x64_f8f6f4(      \
            af[_mt], bg[_nt], acc[_mt][_nt], 0, 0, 0, 0x7F, 0, 0x7F);         \
    __builtin_amdgcn_s_setprio(0);                                            \
  }

  f32x16 acc[2][2] = {};
  int8v af[2], bg[2];

  STAGE(0, 0);
  STAGE(1, BK);                               // vm out: 6

  int cur = 0;
  for (int kt = 0; kt < KT; ++kt) {
    if (kt < KT - 1) { WAITV3(); } else { WAITV0(); }   // tile kt landed (own)
    BAR();                                              // landed for everyone

    LOAD_FRAGS_ALL(cur);                      // 8 ds_read_b128
    WAITL();                                  // all reads of buf[cur] done
    BAR();                                    // done for everyone -> buf free
    if (kt < KT - 2) STAGE(cur, (kt + 2) * BK);  // overlapped with MFMAs
    MFMA_ALL();                               // 4 x mfma_scale 32x32x64

    cur ^= 1;
  }

  // epilogue: 32x32 C/D layout; NON-TEMPORAL stores (C never re-read).
  float* Cb = C + (size_t)bz * LD * LD;
#pragma unroll
  for (int mt = 0; mt < 2; ++mt) {
    int rowb = tm + wr * 64 + mt * 32 + 4 * (lane >> 5);
#pragma unroll
    for (int nt = 0; nt < 2; ++nt) {
      int col = tn + wc * 64 + nt * 32 + l31;
#pragma unroll
      for (int reg = 0; reg < 16; ++reg) {
        int row = rowb + (reg & 3) + 8 * (reg >> 2);
        __builtin_nontemporal_store(acc[mt][nt][reg],
                                    &Cb[(size_t)row * LD + col]);
      }
    }
  }
#undef STAGE
#undef LOAD_FRAGS_ALL
#undef MFMA_ALL
}

extern "C" void kernel_launch(void* const* d_in, const int* in_sizes, int n_in,
                              void* d_out, int out_size, void* d_ws, size_t ws_size,
                              hipStream_t stream) {
  const float* seq_prev  = (const float*)d_in[0];  // [16][2048][768]
  const float* seq_after = (const float*)d_in[1];  // [16][2048][768]
  const float* W         = (const float*)d_in[2];  // [768][768] (in,out)
  const float* bias      = (const float*)d_in[3];  // [768]
  float* out             = (float*)d_out;          // [16][2048][2048] fp32

  char* ws           = (char*)d_ws;
  short* Wt          = (short*)ws;                 // 768*768*2 = 1179648 B
  unsigned char* P8  = (unsigned char*)(ws + 1179648);  // 65536*768 fp8 = 48 MB

  constexpr int NSEQ = 16 * 2048 * 768;            // elems (=bytes in fp8)

  // 1. W transpose + convert
  wt_kernel<<<768 * 768 / 256, 256, 0, stream>>>(W, Wt);

  // 2. feed-forward + relu -> fp8 (1536 blocks, XCD-swizzled)
  gemm_ff<<<1536, 512, 0, stream>>>(seq_prev, seq_after, Wt, bias, P8);

  // 3. batched similarity in MX-fp8 (2048 blocks, XCD-swizzled)
  gemm_sim<<<2048, 512, 0, stream>>>(P8, P8 + NSEQ, out);
}

// Round 25
// 185.655 us; speedup vs baseline: 1.1390x; 1.1390x over previous
//
#include <hip/hip_runtime.h>
#include <hip/hip_bf16.h>
#include <hip/hip_fp8.h>

// sim[b,l,m] = sum_d relu(prev@W+b)[b,l,d] * relu(after@W+b)[b,m,d]
// bz=16, L=2048, d=768.
//
// Pipeline:
//   1. wt_kernel : Wt[n][k] = bf16(W[k][n])                    (ws, 1.2 MB)
//   2. gemm_ff   : P8 = fp8(relu(bf16(seq) @ Wt^T + bias))     (ws, 48 MB)
//   3. gemm_sim  : sim[b] = P8p[b] @ P8a[b]^T -> fp32 d_out    (MX-fp8 MFMA)
//
// ROUND 23 CONFIG EXACTLY (session best, 185.9us). Round-24 lesson locked
// in: non-temporal stores only pay on full-cacheline streams (gemm_sim's
// contiguous fp32 C: -30us); on byte-granular epilogues (ff's fp8 P8) nt
// bypasses the L2 write-combiner -> partial-line HBM writes, WRITE_SIZE
// 49->89MB, +64us. ff keeps CACHED P8 stores; sim keeps NT C stores.

typedef __attribute__((ext_vector_type(8)))  short bf16x8v;
typedef __attribute__((ext_vector_type(8)))  short s16x8;
typedef __attribute__((ext_vector_type(4)))  float f32x4;
typedef __attribute__((ext_vector_type(16))) float f32x16;
typedef __attribute__((ext_vector_type(4)))  float float4v;
typedef __attribute__((ext_vector_type(8)))  int   int8v;
typedef __attribute__((ext_vector_type(4)))  int   int4v;

__device__ __forceinline__ unsigned short f2bf(float f) {
  unsigned int u = __float_as_uint(f);
  u += 0x7fffu + ((u >> 16) & 1u);
  return (unsigned short)(u >> 16);
}

__device__ __forceinline__ unsigned char f2e4m3(float f) {
  __hip_fp8_e4m3 q(f);                        // OCP e4m3fn, RNE+sat
  return (unsigned char)q.__x;
}

__device__ __forceinline__ void async_copy16(void* lds, const void* g) {
  __builtin_amdgcn_global_load_lds(
      (const __attribute__((address_space(1))) void*)g,
      (__attribute__((address_space(3))) void*)lds, 16, 0, 0);
}

// proven macro set (round-5 skeleton)
#define BAR()    asm volatile("s_barrier" ::: "memory")
#define WAITV3() asm volatile("s_waitcnt vmcnt(3)" ::: "memory")
#define WAITV0() asm volatile("s_waitcnt vmcnt(0)" ::: "memory")
#define WAITL()  do { asm volatile("s_waitcnt lgkmcnt(0)" ::: "memory"); \
                      __builtin_amdgcn_sched_barrier(0); } while (0)
// pinned variants (gemm_ff)
#define FBARF()   do { __builtin_amdgcn_sched_barrier(0);                 \
                       __builtin_amdgcn_s_barrier();                      \
                       __builtin_amdgcn_sched_barrier(0); } while (0)
#define FWAITV(n) do { asm volatile("s_waitcnt vmcnt(" #n ")" ::: "memory"); \
                       __builtin_amdgcn_sched_barrier(0); } while (0)
#define FLGKM0()  do { asm volatile("s_waitcnt lgkmcnt(0)" ::: "memory");  \
                       __builtin_amdgcn_sched_barrier(0); } while (0)

// ---------------- W transpose + convert: Wt[n][k] = bf16(W[k][n]) ------------
__global__ void wt_kernel(const float* __restrict__ W, short* __restrict__ Wt) {
  int idx = blockIdx.x * 256 + threadIdx.x;   // n*768 + k
  int n = idx / 768;
  int k = idx - n * 768;
  Wt[idx] = (short)f2bf(W[k * 768 + n]);
}

// ======== gemm_ff: P8 = fp8(relu(bf16(seq) @ Wt^T + bias)) ==================
// 128x256 tile, BK=32, KT=24, 8 waves 2Mx4N (64x64/wave, 32x32x16 frags).
// A: fp32 -> regs -> cvt -> swizzled ds_write (once per element, off path).
__global__ __launch_bounds__(512, 4)
void gemm_ff(const float* __restrict__ Sprev, const float* __restrict__ Safter,
             const short* __restrict__ Wt, const float* __restrict__ bias,
             unsigned char* __restrict__ Out) {
  constexpr int BK = 32, KT = 24;             // K = 768
  __shared__ __align__(16) short lA[2][128 * BK];   // 8 KB per buf
  __shared__ __align__(16) short lB[2][256 * BK];   // 16 KB per buf

  // T1: XCD-chunked swizzle (1536 = 8 * 192, bijective); 3 N-siblings of one
  // by are consecutive -> share the 384KB A-panel in the XCD's L2.
  const int bid  = blockIdx.x;                // 0..1535
  const int virt = (bid & 7) * 192 + (bid >> 3);
  const int by   = virt / 3;                  // 0..511 (M-tile, 128 rows)
  const int bx   = virt - by * 3;             // 0..2   (N-tile, 256 cols)

  const int tid  = threadIdx.x;
  const int lane = tid & 63;
  const int w    = tid >> 6;                  // 0..7
  const int wr   = w >> 2;                    // 0..1 (M half: 64 rows)
  const int wc   = w & 3;                     // 0..3 (N quarter: 64 cols)
  const int tn   = bx * 256;

  const float* Af = (by < 256 ? Sprev : Safter) + (size_t)((by & 255) * 128) * 768;
  const int    tm = by * 128;                 // global output row base

  const int l31  = lane & 31;
  const int khi  = lane >> 5;                 // k-half selector (bytes *16)
  const int arow = wr * 64 + l31;             // A frag row base (0..127)
  const int brow = wc * 64 + l31;             // B frag row base (0..255)
  const int swA  = ((arow >> 1) & 3) << 4;    // 64B-row swizzle, +32 invariant
  const int swB  = ((brow >> 1) & 3) << 4;

  // A: 128x32 fp32 tile; thread: row=tid>>2, 8 floats at col (tid&3)*8.
#define FF_LOAD_A(k0)                                                         \
  {                                                                           \
    int _row = tid >> 2;                                                      \
    const float* _g = Af + (size_t)_row * 768 + (k0) + (tid & 3) * 8;         \
    ar[0] = *(const float4v*)_g;                                              \
    ar[1] = *(const float4v*)(_g + 4);                                        \
  }

  // cvt + swizzled ds_write_b128 (dest XOR'd; read uses same XOR)
#define FF_CVT_WRITE(buf)                                                     \
  {                                                                           \
    int _row = tid >> 2;                                                      \
    int _cb  = ((tid & 3) * 16) ^ (((_row >> 1) & 3) << 4);                   \
    s16x8 _o;                                                                 \
    _o[0] = (short)f2bf(ar[0][0]); _o[1] = (short)f2bf(ar[0][1]);             \
    _o[2] = (short)f2bf(ar[0][2]); _o[3] = (short)f2bf(ar[0][3]);             \
    _o[4] = (short)f2bf(ar[1][0]); _o[5] = (short)f2bf(ar[1][1]);             \
    _o[6] = (short)f2bf(ar[1][2]); _o[7] = (short)f2bf(ar[1][3]);             \
    *(s16x8*)((char*)lA[buf] + _row * 64 + _cb) = _o;                         \
  }

  // B: 256x32 bf16 tile = 16KB = 2 gload_lds rounds, pre-swizzled source
#define FF_STAGE_B(buf, k0)                                                   \
  {                                                                           \
    _Pragma("unroll")                                                         \
    for (int _j = 0; _j < 2; ++_j) {                                          \
      int _c   = _j * 512 + tid;                                              \
      int _row = _c >> 2;                                                     \
      int _cb  = ((_c & 3) * 16) ^ (((_row >> 1) & 3) << 4);                  \
      async_copy16((char*)lB[buf] + _j * 8192 + w * 1024,                     \
                   (const char*)(Wt + (size_t)(tn + _row) * 768 + (k0)) + _cb); \
    }                                                                         \
  }

  // per ks (K=16): 2 A-frags + 2 B-frags, each one ds_read_b128
#define FF_FRAGS(buf, ks)                                                     \
  {                                                                           \
    const char* _bA = (const char*)lA[buf];                                   \
    const char* _bB = (const char*)lB[buf];                                   \
    const int _kxA = ((ks) * 32 + khi * 16) ^ swA;                            \
    const int _kxB = ((ks) * 32 + khi * 16) ^ swB;                            \
    _Pragma("unroll")                                                         \
    for (int _mt = 0; _mt < 2; ++_mt)                                         \
      af[_mt] = *(const bf16x8v*)(_bA + (arow + _mt * 32) * 64 + _kxA);       \
    _Pragma("unroll")                                                         \
    for (int _nt = 0; _nt < 2; ++_nt)                                         \
      bg[_nt] = *(const bf16x8v*)(_bB + (brow + _nt * 32) * 64 + _kxB);       \
  }

#define FF_MFMA()                                                             \
  {                                                                           \
    __builtin_amdgcn_s_setprio(1);                                            \
    _Pragma("unroll")                                                         \
    for (int _mt = 0; _mt < 2; ++_mt)                                         \
      _Pragma("unroll")                                                       \
      for (int _nt = 0; _nt < 2; ++_nt)                                       \
        acc[_mt][_nt] = __builtin_amdgcn_mfma_f32_32x32x16_bf16(              \
            af[_mt], bg[_nt], acc[_mt][_nt], 0, 0, 0);                        \
    __builtin_amdgcn_s_setprio(0);                                            \
  }

  f32x16 acc[2][2] = {};
  float4v ar[2];
  bf16x8v af[2], bg[2];

  // prologue: A(0)->regs->lA[0]; A(1)->regs; B(0),B(1) staged.
  FF_LOAD_A(0);                               // vm: A0=2
  FWAITV(0);
  FF_CVT_WRITE(0);
  FF_LOAD_A(BK);                              // vm: A1=2
  FF_STAGE_B(0, 0);                           // vm: +B0=2
  FF_STAGE_B(1, BK);                          // vm: +B1=2  (out: 6)
  FLGKM0();                                   // own lA[0] writes done
  FWAITV(2);                                  // retires A1+B0: B0 landed
  FBARF();                                    // tile0 ready for everyone

  // invariant at loop top (kt>=1): outstanding = [A(kt+1)(2), B(kt+1)(2)];
  // kt=0: [B1(2)] with A(1) already landed (prologue FWAITV(2)).
  for (int kt = 0; kt < KT; ++kt) {
    const int cur = kt & 1, nxt = cur ^ 1;
    FF_FRAGS(cur, 0);                         // 4 ds_read
    if (kt + 1 < KT) {
      FWAITV(2);                              // A(kt+1) landed (retires oldest)
      FF_CVT_WRITE(nxt);                      // 1 ds_write -> lA[nxt]
    }
    FLGKM0();                                 // frags + write done
    FF_MFMA();                                // ks0
    if (kt + 2 < KT) FF_LOAD_A((kt + 2) * BK);  // 2 vm (ar freed by CVT)
    FF_FRAGS(cur, 1);                         // 4 ds_read
    FLGKM0();                                 // all reads of buf[cur] done
    if (kt + 1 < KT) {
      if (kt + 2 < KT) { FWAITV(2); }         // B(kt+1) landed (leaves A(kt+2))
      else             { FWAITV(0); }         // tail drain
      FBARF();                                // tile kt+1 ready; buf[cur] free
      if (kt + 2 < KT) FF_STAGE_B(cur, (kt + 2) * BK);  // 2 vm
    }
    FF_MFMA();                                // ks1
  }

  // epilogue: bias+relu -> fp8 e4m3 (CACHED stores: byte-granular writes
  // need the L2 write-combiner — r24 nt attempt cost +64us).
#pragma unroll
  for (int mt = 0; mt < 2; ++mt) {
    int rowb = tm + wr * 64 + mt * 32 + 4 * (lane >> 5);
#pragma unroll
    for (int nt = 0; nt < 2; ++nt) {
      int col = tn + wc * 64 + nt * 32 + l31;
      float bv = bias[col];
#pragma unroll
      for (int reg = 0; reg < 16; ++reg) {
        int row = rowb + (reg & 3) + 8 * (reg >> 2);
        float v = fmaxf(acc[mt][nt][reg] + bv, 0.0f);
        Out[(size_t)row * 768 + col] = f2e4m3(v);
      }
    }
  }
#undef FF_LOAD_A
#undef FF_CVT_WRITE
#undef FF_STAGE_B
#undef FF_FRAGS
#undef FF_MFMA
}

// ======== gemm_sim: sim[b] = P8p[b] @ P8a[b]^T (MX-scaled fp8 MFMA) =========
// Round-19 kernel + NON-TEMPORAL C-stores (full-line fp32 stream: -30us).
__global__ __launch_bounds__(512, 4)
void gemm_sim(const unsigned char* __restrict__ A, const unsigned char* __restrict__ B,
              float* __restrict__ C) {
  constexpr int BK = 64, KT = 12, LD = 2048;  // K = 768 (BK elems = bytes)
  __shared__ __align__(16) unsigned char lA[2][256 * BK];   // 16 KB per buf
  __shared__ __align__(16) unsigned char lB[2][128 * BK];   // 8 KB per buf

  // T1: XCD-chunked swizzle (2048 = 8 * 256, bijective).
  const int bid  = blockIdx.x;                // 0..2047
  const int virt = (bid & 7) * 256 + (bid >> 3);
  const int bz   = virt >> 7;                 // 0..15 batch
  const int rem  = virt & 127;
  const int by   = rem >> 4;                  // 0..7  M-tile (256 rows)
  const int bx   = rem & 15;                  // 0..15 N-tile (128 rows)

  const int tid  = threadIdx.x;
  const int lane = tid & 63;
  const int w    = tid >> 6;                  // 0..7
  const int wr   = w >> 1;                    // 0..3  (M quarter: 64 rows)
  const int wc   = w & 1;                     // 0..1  (N half: 64 cols)
  const int tm   = by * 256;
  const int tn   = bx * 128;

  const unsigned char* Ab = A + (size_t)bz * LD * 768 + (size_t)tm * 768;
  const unsigned char* Bb = B + (size_t)bz * LD * 768 + (size_t)tn * 768;

  const int l31  = lane & 31;                 // fragment row within 32
  const int kq32 = (lane >> 5) * 32;          // byte base of lane's 32B k-slice
  const int arow = wr * 64 + l31;             // A row base (0..255)
  const int brow = wc * 64 + l31;             // B row base (0..127)
  const int swA  = ((arow >> 1) & 3) << 4;
  const int swB  = ((brow >> 1) & 3) << 4;

#define STAGE(buf, k0)                                                        \
  {                                                                           \
    _Pragma("unroll")                                                         \
    for (int _j = 0; _j < 2; ++_j) {                                          \
      int _c   = _j * 512 + tid;                                              \
      int _row = _c >> 2;                                                     \
      int _cb  = ((_c & 3) * 16) ^ (((_row >> 1) & 3) << 4);                  \
      async_copy16((char*)lA[buf] + _j * 8192 + w * 1024,                     \
                   Ab + (size_t)_row * 768 + (k0) + _cb);                     \
    }                                                                         \
    {                                                                         \
      int _row = tid >> 2;                                                    \
      int _cb  = ((tid & 3) * 16) ^ (((_row >> 1) & 3) << 4);                 \
      async_copy16((char*)lB[buf] + w * 1024,                                 \
                   Bb + (size_t)_row * 768 + (k0) + _cb);                     \
    }                                                                         \
  }

#define LOAD_FRAGS_ALL(buf)                                                   \
  {                                                                           \
    const char* _bA = (const char*)lA[buf];                                   \
    const char* _bB = (const char*)lB[buf];                                   \
    _Pragma("unroll")                                                         \
    for (int _mt = 0; _mt < 2; ++_mt) {                                       \
      const char* _r = _bA + (arow + _mt * 32) * BK;                          \
      int4v _lo = *(const int4v*)(_r + ((kq32 + 0)  ^ swA));                  \
      int4v _hi = *(const int4v*)(_r + ((kq32 + 16) ^ swA));                  \
      af[_mt][0] = _lo[0]; af[_mt][1] = _lo[1];                               \
      af[_mt][2] = _lo[2]; af[_mt][3] = _lo[3];                               \
      af[_mt][4] = _hi[0]; af[_mt][5] = _hi[1];                               \
      af[_mt][6] = _hi[2]; af[_mt][7] = _hi[3];                               \
    }                                                                         \
    _Pragma("unroll")                                                         \
    for (int _nt = 0; _nt < 2; ++_nt) {                                       \
      const char* _r = _bB + (brow + _nt * 32) * BK;                          \
      int4v _lo = *(const int4v*)(_r + ((kq32 + 0)  ^ swB));                  \
      int4v _hi = *(const int4v*)(_r + ((kq32 + 16) ^ swB));                  \
      bg[_nt][0] = _lo[0]; bg[_nt][1] = _lo[1];                               \
      bg[_nt][2] = _lo[2]; bg[_nt][3] = _lo[3];                               \
      bg[_nt][4] = _hi[0]; bg[_nt][5] = _hi[1];                               \
      bg[_nt][6] = _hi[2]; bg[_nt][7] = _hi[3];                               \
    }                                                                         \
  }

#define MFMA_ALL()                                                            \
  {                                                                           \
    __builtin_amdgcn_s_setprio(1);                                            \
    _Pragma("unroll")                                                         \
    for (int _mt = 0; _mt < 2; ++_mt)                                         \
      _Pragma("unroll")                                                       \
      for (int _nt = 0; _nt < 2; ++_nt)                                       \
        acc[_mt][_nt] = __builtin_amdgcn_mfma_scale_f32_32x32x64_f8f6f4(      \
            af[_mt], bg[_nt], acc[_mt][_nt], 0, 0, 0, 0x7F, 0, 0x7F);         \
    __builtin_amdgcn_s_setprio(0);                                            \
  }

  f32x16 acc[2][2] = {};
  int8v af[2], bg[2];

  STAGE(0, 0);
  STAGE(1, BK);                               // vm out: 6

  int cur = 0;
  for (int kt = 0; kt < KT; ++kt) {
    if (kt < KT - 1) { WAITV3(); } else { WAITV0(); }   // tile kt landed (own)
    BAR();                                              // landed for everyone

    LOAD_FRAGS_ALL(cur);                      // 8 ds_read_b128
    WAITL();                                  // all reads of buf[cur] done
    BAR();                                    // done for everyone -> buf free
    if (kt < KT - 2) STAGE(cur, (kt + 2) * BK);  // overlapped with MFMAs
    MFMA_ALL();                               // 4 x mfma_scale 32x32x64

    cur ^= 1;
  }

  // epilogue: 32x32 C/D layout; NON-TEMPORAL stores (C never re-read;
  // write-around keeps P8 panels resident in the XCD L2).
  float* Cb = C + (size_t)bz * LD * LD;
#pragma unroll
  for (int mt = 0; mt < 2; ++mt) {
    int rowb = tm + wr * 64 + mt * 32 + 4 * (lane >> 5);
#pragma unroll
    for (int nt = 0; nt < 2; ++nt) {
      int col = tn + wc * 64 + nt * 32 + l31;
#pragma unroll
      for (int reg = 0; reg < 16; ++reg) {
        int row = rowb + (reg & 3) + 8 * (reg >> 2);
        __builtin_nontemporal_store(acc[mt][nt][reg],
                                    &Cb[(size_t)row * LD + col]);
      }
    }
  }
#undef STAGE
#undef LOAD_FRAGS_ALL
#undef MFMA_ALL
}

extern "C" void kernel_launch(void* const* d_in, const int* in_sizes, int n_in,
                              void* d_out, int out_size, void* d_ws, size_t ws_size,
                              hipStream_t stream) {
  const float* seq_prev  = (const float*)d_in[0];  // [16][2048][768]
  const float* seq_after = (const float*)d_in[1];  // [16][2048][768]
  const float* W         = (const float*)d_in[2];  // [768][768] (in,out)
  const float* bias      = (const float*)d_in[3];  // [768]
  float* out             = (float*)d_out;          // [16][2048][2048] fp32

  char* ws           = (char*)d_ws;
  short* Wt          = (short*)ws;                 // 768*768*2 = 1179648 B
  unsigned char* P8  = (unsigned char*)(ws + 1179648);  // 65536*768 fp8 = 48 MB

  constexpr int NSEQ = 16 * 2048 * 768;            // elems (=bytes in fp8)

  // 1. W transpose + convert
  wt_kernel<<<768 * 768 / 256, 256, 0, stream>>>(W, Wt);

  // 2. feed-forward + relu -> fp8 (1536 blocks, XCD-swizzled)
  gemm_ff<<<1536, 512, 0, stream>>>(seq_prev, seq_after, Wt, bias, P8);

  // 3. batched similarity in MX-fp8 (2048 blocks, XCD-swizzled)
  gemm_sim<<<2048, 512, 0, stream>>>(P8, P8 + NSEQ, out);
}